// Round 16
// baseline (279.957 us; speedup 1.0000x reference)
//
#include <hip/hip_runtime.h>

// LSTMClassifier round 15: anti-phased halves (mid-iteration barrier).
//   grid = 256 blocks x 512 threads (8 waves). Block = 8 batch rows.
//   Iter k, two halves:
//     HALF1: L0 waves: ds_read h0(k-1) + 8 MFMA  (matrix pipe)
//            L1 waves: epilogue of acc(k-1) -> h1(k-2), write bufB[k&1] (VALU)
//     [mid __syncthreads]
//     HALF2: L0 waves: epilogue -> h0(k), write bufA[k&1]          (VALU)
//            L1 waves: ds_read h0(k-1), h1(k-2) + 16 MFMA -> acc   (matrix)
//     [end __syncthreads]
//   -> MFMA and VALU phases of the two roles are anti-aligned; the SIMD
//   overlaps them (m114). acc1 persists in regs across the end barrier.
//   Timeline: L0 computes h0(k) at iter k (k<=511); L1's epi at iter k
//   produces h1(k-2) (k=2..513); L1's MFMA at iter k produces gates for
//   h1(k-1) (k=1..512). Math identical to round 14 (pure retiming).
//   Batch row b -> M-row 4*(b>>1)+(b&1); junk M-rows stay 0.
//   XOR-rotated h layout; packed float2 epilogue; merged-rcp activations
//   (5 exp2 + 2 rcp per cell); -log2e pre-scaled weights/biases.

typedef _Float16 half8    __attribute__((ext_vector_type(8)));
typedef float    float4_t __attribute__((ext_vector_type(4)));
typedef float    float2v  __attribute__((ext_vector_type(2)));

#define T_STEPS 512
#define SIG_K  (-1.442695040888963f)    // -log2(e)
#define TANH_K (-2.885390081777927f)    // -2*log2(e)

__device__ __forceinline__ int hoff(int slot, int row, int kb, int lo) {
    return slot * 1024 + row * 64 + (((kb + row) & 7) << 3) + lo;
}

// Packed 2-cell LSTM epilogue (inputs pre-scaled & bias-folded).
__device__ __forceinline__ float2v lstm_cell2(float2v zi, float2v zf,
                                              float2v zg, float2v zo,
                                              float2v& c) {
    float2v ei, ef, vv, eo;
    ei[0] = __builtin_amdgcn_exp2f(zi[0]); ei[1] = __builtin_amdgcn_exp2f(zi[1]);
    ef[0] = __builtin_amdgcn_exp2f(zf[0]); ef[1] = __builtin_amdgcn_exp2f(zf[1]);
    vv[0] = __builtin_amdgcn_exp2f(zg[0]); vv[1] = __builtin_amdgcn_exp2f(zg[1]);
    eo[0] = __builtin_amdgcn_exp2f(zo[0]); eo[1] = __builtin_amdgcn_exp2f(zo[1]);
    const float2v one = {1.f, 1.f};
    const float2v pi = one + ei, pf = one + ef, pv = one + vv, po = one + eo;
    const float2v A   = pi * pv;
    const float2v num = c * A + (one - vv) * pf;
    const float2v d   = pf * A;
    float2v rd;
    rd[0] = __builtin_amdgcn_rcpf(d[0]); rd[1] = __builtin_amdgcn_rcpf(d[1]);
    const float2v cn = num * rd;
    c = cn;
    const float2v ct = cn * TANH_K;
    float2v u;
    u[0] = __builtin_amdgcn_exp2f(ct[0]); u[1] = __builtin_amdgcn_exp2f(ct[1]);
    const float2v den = po * (one + u);
    float2v rn;
    rn[0] = __builtin_amdgcn_rcpf(den[0]); rn[1] = __builtin_amdgcn_rcpf(den[1]);
    return (one - u) * rn;
}

extern "C" __global__ __launch_bounds__(512, 1)
void lstm2_mfma(const float* __restrict__ x,
                const float* __restrict__ w_ih0, const float* __restrict__ w_hh0,
                const float* __restrict__ b_ih0, const float* __restrict__ b_hh0,
                const float* __restrict__ w_ih1, const float* __restrict__ w_hh1,
                const float* __restrict__ b_ih1, const float* __restrict__ b_hh1,
                const float* __restrict__ w_fc,  const float* __restrict__ b_fc,
                float* __restrict__ out)
{
    __shared__ float    x_lds[T_STEPS][8];     // 16 KB
    __shared__ _Float16 bufA[2 * 1024];        // h0, 2 slots, 4 KB
    __shared__ _Float16 bufB[2 * 1024];        // h1, 2 slots, 4 KB
    __shared__ float    hfin[8][68];

    const int tid  = threadIdx.x;
    const int wv   = tid >> 6;          // wave 0..7
    const int lane = tid & 63;
    const int cr   = lane & 15;         // A-row (M-row) / C-col (unit)
    const int kg   = lane >> 4;         // k-group 0..3
    const int rb   = kg * 4;            // C-frag row base (cells at rb, rb+1)
    const int b0   = blockIdx.x * 8;    // this block's 8 batch rows
    const bool isL0 = (wv < 4);
    const int u    = wv & 3;            // unit tile 0..3
    const int ucol = u * 16 + cr;       // this lane's unit 0..63
    const int wkb  = 2 * u + (cr >> 3); // write-side 8-half block index

    // ---- stage x; zero h bufs ----
    for (int idx = tid; idx < 8 * T_STEPS; idx += 512) {
        const int r = idx >> 9, t = idx & (T_STEPS - 1);
        x_lds[t][r] = x[(long)(b0 + r) * T_STEPS + t];
    }
    for (int idx = tid; idx < 2 * 1024; idx += 512) {
        bufA[idx] = (_Float16)0.f;      // junk M-rows stay 0 forever
        bufB[idx] = (_Float16)0.f;
    }

    // ---- per-lane weight fragments (registers), role-specialized ----
    half8 wf[4][4];                 // L0 uses [g][0..1]; L1 uses [g][0..3]
    float4_t bias4[4];              // gate bias broadcast (MFMA C-init)
    float2v  wi0b[4];               // L0: x-weight broadcast pair
    #pragma unroll
    for (int g = 0; g < 4; ++g) {
        const float sc = (g == 2) ? TANH_K : SIG_K;   // gate 2 = g (tanh)
        const int col = g * 64 + ucol;                // PyTorch i,f,g,o
        if (isL0) {
            const float b = (b_ih0[col] + b_hh0[col]) * sc;
            bias4[g] = (float4_t){b, b, b, b};
            const float w = w_ih0[col] * sc;
            wi0b[g] = (float2v){w, w};
            #pragma unroll
            for (int kt = 0; kt < 2; ++kt) {
                const float* src = w_hh0 + col * 64 + kt * 32 + kg * 8;
                #pragma unroll
                for (int i = 0; i < 8; ++i) wf[g][kt][i] = (_Float16)(src[i] * sc);
            }
        } else {
            const float b = (b_ih1[col] + b_hh1[col]) * sc;
            bias4[g] = (float4_t){b, b, b, b};
            wi0b[g] = (float2v){0.f, 0.f};
            #pragma unroll
            for (int kt = 0; kt < 4; ++kt) {
                const int k0 = kt * 32 + kg * 8;   // 0..119 in [h0;h1]
                const float* src = (k0 < 64) ? (w_ih1 + col * 64 + k0)
                                             : (w_hh1 + col * 64 + (k0 - 64));
                #pragma unroll
                for (int i = 0; i < 8; ++i) wf[g][kt][i] = (_Float16)(src[i] * sc);
            }
        }
    }

    // ---- hoisted LDS offsets (halfs), both slots (same values for A & B) ----
    const int rd0s0 = hoff(0, cr, kg,     0), rd0s1 = hoff(1, cr, kg,     0);
    const int rd1s0 = hoff(0, cr, 4 + kg, 0), rd1s1 = hoff(1, cr, 4 + kg, 0);
    const int w0s0  = hoff(0, rb,     wkb, cr & 7);
    const int w1s0  = hoff(0, rb + 1, wkb, cr & 7);
    const int w0s1  = hoff(1, rb,     wkb, cr & 7);
    const int w1s1  = hoff(1, rb + 1, wkb, cr & 7);

    float2v cc2 = {0.f, 0.f};
    float2v hv2 = {0.f, 0.f};
    float4_t acc0[4];                   // L0: intra-iter accs
    float4_t acc1[4];                   // L1: accs persist across end-barrier
    #pragma unroll
    for (int g = 0; g < 4; ++g) { acc0[g] = bias4[g]; acc1[g] = bias4[g]; }

    auto l0_mfma = [&](int rd0, int rd1) __attribute__((always_inline)) {
        const half8 a0 = *(const half8*)&bufA[rd0];
        const half8 a1 = *(const half8*)&bufA[rd1];
        #pragma unroll
        for (int g = 0; g < 4; ++g) {
            acc0[g] = __builtin_amdgcn_mfma_f32_16x16x32_f16(a0, wf[g][0], bias4[g], 0, 0, 0);
            acc0[g] = __builtin_amdgcn_mfma_f32_16x16x32_f16(a1, wf[g][1], acc0[g], 0, 0, 0);
        }
    };
    auto l0_epi = [&](int kk, int wo0, int wo1) __attribute__((always_inline)) {
        const float2v xq = *(const float2v*)&x_lds[kk][2 * kg];
        float2v z[4];
        #pragma unroll
        for (int g = 0; g < 4; ++g) {
            const float2v ap = {acc0[g][0], acc0[g][1]};
            z[g] = xq * wi0b[g] + ap;          // pk_fma
        }
        const float2v h = lstm_cell2(z[0], z[1], z[2], z[3], cc2);
        bufA[wo0] = (_Float16)h[0];
        bufA[wo1] = (_Float16)h[1];
    };
    auto l1_mfma = [&](int rd0, int rd1, int rB0, int rB1) __attribute__((always_inline)) {
        const half8 a0  = *(const half8*)&bufA[rd0];
        const half8 a1  = *(const half8*)&bufA[rd1];
        const half8 bh0 = *(const half8*)&bufB[rB0];
        const half8 bh1 = *(const half8*)&bufB[rB1];
        #pragma unroll
        for (int g = 0; g < 4; ++g) {
            acc1[g] = __builtin_amdgcn_mfma_f32_16x16x32_f16(a0,  wf[g][0], bias4[g], 0, 0, 0);
            acc1[g] = __builtin_amdgcn_mfma_f32_16x16x32_f16(a1,  wf[g][1], acc1[g], 0, 0, 0);
            acc1[g] = __builtin_amdgcn_mfma_f32_16x16x32_f16(bh0, wf[g][2], acc1[g], 0, 0, 0);
            acc1[g] = __builtin_amdgcn_mfma_f32_16x16x32_f16(bh1, wf[g][3], acc1[g], 0, 0, 0);
        }
    };
    auto l1_epi = [&](int wo0, int wo1) __attribute__((always_inline)) {
        float2v z[4];
        #pragma unroll
        for (int g = 0; g < 4; ++g)
            z[g] = (float2v){acc1[g][0], acc1[g][1]};
        hv2 = lstm_cell2(z[0], z[1], z[2], z[3], cc2);
        bufB[wo0] = (_Float16)hv2[0];
        bufB[wo1] = (_Float16)hv2[1];
    };

    __syncthreads();   // staging visible

    // ---- k = 0: L0 computes h0(0) (reads slot1 zeros, writes slot0) ----
    if (isL0) l0_mfma(rd0s1, rd1s1);
    __syncthreads();
    if (isL0) l0_epi(0, w0s0, w1s0);
    __syncthreads();

    // ---- k = 1: L0 h0(1); L1 MFMA -> gates for h1(0) ----
    if (isL0) l0_mfma(rd0s0, rd1s0);
    __syncthreads();
    if (isL0) l0_epi(1, w0s1, w1s1);
    else      l1_mfma(rd0s0, rd1s0, rd0s1, rd1s1);   // h0(0) + h1(-1)=0
    __syncthreads();

    // ---- steady k = 2..511 (255 pairs: even k, odd k+1) ----
    for (int k = 2; k <= 510; k += 2) {
        // even k: h0-slots RS=1 WS=0; bufB write slot0, read slot0
        if (isL0) l0_mfma(rd0s1, rd1s1);
        else      l1_epi(w0s0, w1s0);                // h1(k-2) -> B slot0
        __syncthreads();                             // MID
        if (isL0) l0_epi(k, w0s0, w1s0);
        else      l1_mfma(rd0s1, rd1s1, rd0s0, rd1s0); // h0(k-1) + h1(k-2)
        __syncthreads();                             // END
        // odd k+1: slots flipped
        if (isL0) l0_mfma(rd0s0, rd1s0);
        else      l1_epi(w0s1, w1s1);                // h1(k-1) -> B slot1
        __syncthreads();                             // MID
        if (isL0) l0_epi(k + 1, w0s1, w1s1);
        else      l1_mfma(rd0s0, rd1s0, rd0s1, rd1s1); // h0(k) + h1(k-1)
        __syncthreads();                             // END
    }

    // ---- k = 512 (even): L1 epi -> h1(510); L1 MFMA -> gates h1(511) ----
    if (!isL0) l1_epi(w0s0, w1s0);
    __syncthreads();
    if (!isL0) l1_mfma(rd0s1, rd1s1, rd0s0, rd1s0);  // h0(511) + h1(510)
    __syncthreads();
    // ---- k = 513: L1 epi -> h1(511) (kept in hv2) ----
    if (!isL0) l1_epi(w0s1, w1s1);
    __syncthreads();

    // ---- FC head: h_last = h1(511) ----
    if (!isL0) {
        hfin[2 * kg + 0][ucol] = hv2[0];
        hfin[2 * kg + 1][ucol] = hv2[1];
    }
    __syncthreads();

    if (tid < 24) {
        const int row = tid / 3, cls = tid - row * 3;
        float s = b_fc[cls];
        const float* wr = w_fc + cls * 64;
        #pragma unroll 8
        for (int uu = 0; uu < 64; ++uu) s += hfin[row][uu] * wr[uu];
        out[(long)(b0 + row) * 3 + cls] = s;
    }
}

extern "C" void kernel_launch(void* const* d_in, const int* in_sizes, int n_in,
                              void* d_out, int out_size, void* d_ws, size_t ws_size,
                              hipStream_t stream) {
    const float* xx     = (const float*)d_in[0];
    const float* w_ih0  = (const float*)d_in[1];
    const float* w_hh0  = (const float*)d_in[2];
    const float* b_ih0  = (const float*)d_in[3];
    const float* b_hh0  = (const float*)d_in[4];
    const float* w_ih1  = (const float*)d_in[5];
    const float* w_hh1  = (const float*)d_in[6];
    const float* b_ih1  = (const float*)d_in[7];
    const float* b_hh1  = (const float*)d_in[8];
    const float* w_fc   = (const float*)d_in[9];
    const float* b_fc   = (const float*)d_in[10];
    float* out = (float*)d_out;

    lstm2_mfma<<<dim3(256), dim3(512), 0, stream>>>(
        xx, w_ih0, w_hh0, b_ih0, b_hh0,
        w_ih1, w_hh1, b_ih1, b_hh1, w_fc, b_fc, out);
}

// Round 17
// 220.660 us; speedup vs baseline: 1.2687x; 1.2687x over previous
//
#include <hip/hip_runtime.h>

// LSTMClassifier round 16: round-14 base + s_setprio(1) around MFMA clusters
// (T5). Role-split waves (L0 short chain, L1 long chain) share each SIMD;
// boosting a wave only during its MFMA burst lets the other wave's epilogue
// fill the gaps. No structural/numeric change vs round 14.
//   grid = 256 blocks x 512 threads (8 waves). Block = 8 batch rows.
//   Waves 0-3: L0 tile u: h0(k) = f(h0(k-1))               [k <= 511]
//   Waves 4-7: L1 tile u: h1(k-1) = f(h0(k-1), h1(k-2))    [k >= 1]
//   Batch row b -> M-row 4*(b>>1)+(b&1): acc[g][0..1] real; junk rows stay 0.
//   Unroll-2 k-loop, hoisted LDS offsets, one s_barrier per iter.
//   XOR-rotated h layout; packed float2 epilogue; merged-rcp activations
//   (5 exp2 + 2 rcp per cell); -log2e pre-scaled weights/biases; bias in
//   MFMA C-operand.

typedef _Float16 half8    __attribute__((ext_vector_type(8)));
typedef float    float4_t __attribute__((ext_vector_type(4)));
typedef float    float2v  __attribute__((ext_vector_type(2)));

#define T_STEPS 512
#define SIG_K  (-1.442695040888963f)    // -log2(e)
#define TANH_K (-2.885390081777927f)    // -2*log2(e)

__device__ __forceinline__ int hoff(int slot, int row, int kb, int lo) {
    return slot * 1024 + row * 64 + (((kb + row) & 7) << 3) + lo;
}

// Packed 2-cell LSTM epilogue (inputs pre-scaled & bias-folded).
__device__ __forceinline__ float2v lstm_cell2(float2v zi, float2v zf,
                                              float2v zg, float2v zo,
                                              float2v& c) {
    float2v ei, ef, vv, eo;
    ei[0] = __builtin_amdgcn_exp2f(zi[0]); ei[1] = __builtin_amdgcn_exp2f(zi[1]);
    ef[0] = __builtin_amdgcn_exp2f(zf[0]); ef[1] = __builtin_amdgcn_exp2f(zf[1]);
    vv[0] = __builtin_amdgcn_exp2f(zg[0]); vv[1] = __builtin_amdgcn_exp2f(zg[1]);
    eo[0] = __builtin_amdgcn_exp2f(zo[0]); eo[1] = __builtin_amdgcn_exp2f(zo[1]);
    const float2v one = {1.f, 1.f};
    const float2v pi = one + ei, pf = one + ef, pv = one + vv, po = one + eo;
    const float2v A   = pi * pv;
    const float2v num = c * A + (one - vv) * pf;
    const float2v d   = pf * A;
    float2v rd;
    rd[0] = __builtin_amdgcn_rcpf(d[0]); rd[1] = __builtin_amdgcn_rcpf(d[1]);
    const float2v cn = num * rd;
    c = cn;
    const float2v ct = cn * TANH_K;
    float2v u;
    u[0] = __builtin_amdgcn_exp2f(ct[0]); u[1] = __builtin_amdgcn_exp2f(ct[1]);
    const float2v den = po * (one + u);
    float2v rn;
    rn[0] = __builtin_amdgcn_rcpf(den[0]); rn[1] = __builtin_amdgcn_rcpf(den[1]);
    return (one - u) * rn;
}

extern "C" __global__ __launch_bounds__(512, 1)
void lstm2_mfma(const float* __restrict__ x,
                const float* __restrict__ w_ih0, const float* __restrict__ w_hh0,
                const float* __restrict__ b_ih0, const float* __restrict__ b_hh0,
                const float* __restrict__ w_ih1, const float* __restrict__ w_hh1,
                const float* __restrict__ b_ih1, const float* __restrict__ b_hh1,
                const float* __restrict__ w_fc,  const float* __restrict__ b_fc,
                float* __restrict__ out)
{
    __shared__ float    x_lds[T_STEPS][8];     // 16 KB
    __shared__ _Float16 bufA[2 * 1024];        // h0, 2 slots, 4 KB
    __shared__ _Float16 bufB[2 * 1024];        // h1, 2 slots, 4 KB
    __shared__ float    hfin[8][68];

    const int tid  = threadIdx.x;
    const int wv   = tid >> 6;          // wave 0..7
    const int lane = tid & 63;
    const int cr   = lane & 15;         // A-row (M-row) / C-col (unit)
    const int kg   = lane >> 4;         // k-group 0..3
    const int rb   = kg * 4;            // C-frag row base (cells at rb, rb+1)
    const int b0   = blockIdx.x * 8;    // this block's 8 batch rows
    const bool isL0 = (wv < 4);
    const int u    = wv & 3;            // unit tile 0..3
    const int ucol = u * 16 + cr;       // this lane's unit 0..63
    const int wkb  = 2 * u + (cr >> 3); // write-side 8-half block index

    // ---- stage x[b0..b0+7][t] -> x_lds[t][r]; zero h bufs ----
    for (int idx = tid; idx < 8 * T_STEPS; idx += 512) {
        const int r = idx >> 9, t = idx & (T_STEPS - 1);
        x_lds[t][r] = x[(long)(b0 + r) * T_STEPS + t];
    }
    for (int idx = tid; idx < 2 * 1024; idx += 512) {
        bufA[idx] = (_Float16)0.f;      // junk M-rows stay 0 forever
        bufB[idx] = (_Float16)0.f;
    }

    // ---- per-lane weight fragments (registers), role-specialized ----
    half8 wf[4][4];                 // L0 uses [g][0..1]; L1 uses [g][0..3]
    float4_t bias4[4];              // gate bias broadcast (MFMA C-init)
    float2v  wi0b[4];               // L0: x-weight broadcast pair
    #pragma unroll
    for (int g = 0; g < 4; ++g) {
        const float sc = (g == 2) ? TANH_K : SIG_K;   // gate 2 = g (tanh)
        const int col = g * 64 + ucol;                // PyTorch i,f,g,o
        if (isL0) {
            const float b = (b_ih0[col] + b_hh0[col]) * sc;
            bias4[g] = (float4_t){b, b, b, b};
            const float w = w_ih0[col] * sc;
            wi0b[g] = (float2v){w, w};
            #pragma unroll
            for (int kt = 0; kt < 2; ++kt) {
                const float* src = w_hh0 + col * 64 + kt * 32 + kg * 8;
                #pragma unroll
                for (int i = 0; i < 8; ++i) wf[g][kt][i] = (_Float16)(src[i] * sc);
            }
        } else {
            const float b = (b_ih1[col] + b_hh1[col]) * sc;
            bias4[g] = (float4_t){b, b, b, b};
            wi0b[g] = (float2v){0.f, 0.f};
            #pragma unroll
            for (int kt = 0; kt < 4; ++kt) {
                const int k0 = kt * 32 + kg * 8;   // 0..119 in [h0;h1]
                const float* src = (k0 < 64) ? (w_ih1 + col * 64 + k0)
                                             : (w_hh1 + col * 64 + (k0 - 64));
                #pragma unroll
                for (int i = 0; i < 8; ++i) wf[g][kt][i] = (_Float16)(src[i] * sc);
            }
        }
    }

    // ---- hoisted LDS offsets (in halfs), both slots ----
    const int rd0s0 = hoff(0, cr, kg,     0), rd0s1 = hoff(1, cr, kg,     0);
    const int rd1s0 = hoff(0, cr, 4 + kg, 0), rd1s1 = hoff(1, cr, 4 + kg, 0);
    const int w0s0  = hoff(0, rb,     wkb, cr & 7);
    const int w1s0  = hoff(0, rb + 1, wkb, cr & 7);
    const int w0s1  = hoff(1, rb,     wkb, cr & 7);
    const int w1s1  = hoff(1, rb + 1, wkb, cr & 7);

    float2v cc2 = {0.f, 0.f};           // this lane's 2 cell states
    float2v hv2 = {0.f, 0.f};

    auto l0_step = [&](int kk, int rd0, int rd1, int wo0, int wo1)
        __attribute__((always_inline)) {
        const half8 a0 = *(const half8*)&bufA[rd0];
        const half8 a1 = *(const half8*)&bufA[rd1];
        float4_t acc[4];
        __builtin_amdgcn_s_setprio(1);
        #pragma unroll
        for (int g = 0; g < 4; ++g) {
            acc[g] = __builtin_amdgcn_mfma_f32_16x16x32_f16(a0, wf[g][0], bias4[g], 0, 0, 0);
            acc[g] = __builtin_amdgcn_mfma_f32_16x16x32_f16(a1, wf[g][1], acc[g], 0, 0, 0);
        }
        __builtin_amdgcn_s_setprio(0);
        const float2v xq = *(const float2v*)&x_lds[kk][2 * kg];
        float2v z[4];
        #pragma unroll
        for (int g = 0; g < 4; ++g) {
            const float2v ap = {acc[g][0], acc[g][1]};
            z[g] = xq * wi0b[g] + ap;          // pk_fma
        }
        const float2v h = lstm_cell2(z[0], z[1], z[2], z[3], cc2);
        bufA[wo0] = (_Float16)h[0];
        bufA[wo1] = (_Float16)h[1];
    };
    auto l1_step = [&](int rd0, int rd1, int rB0, int rB1, int wo0, int wo1)
        __attribute__((always_inline)) {
        const half8 a0  = *(const half8*)&bufA[rd0];
        const half8 a1  = *(const half8*)&bufA[rd1];
        const half8 bh0 = *(const half8*)&bufB[rB0];
        const half8 bh1 = *(const half8*)&bufB[rB1];
        float4_t acc[4];
        __builtin_amdgcn_s_setprio(1);
        #pragma unroll
        for (int g = 0; g < 4; ++g) {
            acc[g] = __builtin_amdgcn_mfma_f32_16x16x32_f16(a0,  wf[g][0], bias4[g], 0, 0, 0);
            acc[g] = __builtin_amdgcn_mfma_f32_16x16x32_f16(a1,  wf[g][1], acc[g], 0, 0, 0);
            acc[g] = __builtin_amdgcn_mfma_f32_16x16x32_f16(bh0, wf[g][2], acc[g], 0, 0, 0);
            acc[g] = __builtin_amdgcn_mfma_f32_16x16x32_f16(bh1, wf[g][3], acc[g], 0, 0, 0);
        }
        __builtin_amdgcn_s_setprio(0);
        float2v z[4];
        #pragma unroll
        for (int g = 0; g < 4; ++g)
            z[g] = (float2v){acc[g][0], acc[g][1]};
        hv2 = lstm_cell2(z[0], z[1], z[2], z[3], cc2);
        bufB[wo0] = (_Float16)hv2[0];
        bufB[wo1] = (_Float16)hv2[1];
    };

    __syncthreads();   // x_lds + zeroed bufs visible

    // ---- k = 0 (PH0): L0 only (reads A-s1 = h0(-1)=0, writes A-s0) ----
    if (isL0) l0_step(0, rd0s1, rd1s1, w0s0, w1s0);
    __syncthreads();

    // ---- 255 pairs: (odd k, even k+1), k = 1..509 ----
    for (int k = 1; k <= 509; k += 2) {
        // PH1 (odd k): L0 reads A-s0 writes A-s1; L1 reads A-s0 + B-s1, writes B-s0
        if (isL0) l0_step(k, rd0s0, rd1s0, w0s1, w1s1);
        else      l1_step(rd0s0, rd1s0, rd0s1, rd1s1, w0s0, w1s0);
        __syncthreads();
        // PH0 (even k+1): L0 reads A-s1 writes A-s0; L1 reads A-s1 + B-s0, writes B-s1
        if (isL0) l0_step(k + 1, rd0s1, rd1s1, w0s0, w1s0);
        else      l1_step(rd0s1, rd1s1, rd0s0, rd1s0, w0s1, w1s1);
        __syncthreads();
    }

    // ---- k = 511 (PH1): L0 last step + L1 ----
    if (isL0) l0_step(511, rd0s0, rd1s0, w0s1, w1s1);
    else      l1_step(rd0s0, rd1s0, rd0s1, rd1s1, w0s0, w1s0);
    __syncthreads();
    // ---- k = 512 (PH0): L1 only (h1(511)) ----
    if (!isL0) l1_step(rd0s1, rd1s1, rd0s0, rd1s0, w0s1, w1s1);
    __syncthreads();

    // ---- FC head: h_last = h1(511), held by L1 waves (2 batch rows each) ----
    if (!isL0) {
        hfin[2 * kg + 0][ucol] = hv2[0];
        hfin[2 * kg + 1][ucol] = hv2[1];
    }
    __syncthreads();

    if (tid < 24) {
        const int row = tid / 3, cls = tid - row * 3;
        float s = b_fc[cls];
        const float* wr = w_fc + cls * 64;
        #pragma unroll 8
        for (int uu = 0; uu < 64; ++uu) s += hfin[row][uu] * wr[uu];
        out[(long)(b0 + row) * 3 + cls] = s;
    }
}

extern "C" void kernel_launch(void* const* d_in, const int* in_sizes, int n_in,
                              void* d_out, int out_size, void* d_ws, size_t ws_size,
                              hipStream_t stream) {
    const float* xx     = (const float*)d_in[0];
    const float* w_ih0  = (const float*)d_in[1];
    const float* w_hh0  = (const float*)d_in[2];
    const float* b_ih0  = (const float*)d_in[3];
    const float* b_hh0  = (const float*)d_in[4];
    const float* w_ih1  = (const float*)d_in[5];
    const float* w_hh1  = (const float*)d_in[6];
    const float* b_ih1  = (const float*)d_in[7];
    const float* b_hh1  = (const float*)d_in[8];
    const float* w_fc   = (const float*)d_in[9];
    const float* b_fc   = (const float*)d_in[10];
    float* out = (float*)d_out;

    lstm2_mfma<<<dim3(256), dim3(512), 0, stream>>>(
        xx, w_ih0, w_hh0, b_ih0, b_hh0,
        w_ih1, w_hh1, b_ih1, b_hh1, w_fc, b_fc, out);
}